// Round 1
// baseline (1608.576 us; speedup 1.0000x reference)
//
#include <hip/hip_runtime.h>
#include <hip/hip_bf16.h>

// FactoredLSTM on MI355X (gfx950).
// Phases:
//   A) convert/transpose weights fp32->bf16 [N][K]; gather embeddings; batched
//      GEMM chain U = X@Uw, S = U@S1w, Gx = S@Vw + (V_b + W_b)  (no h dependence)
//   B) 63 sequential fused step kernels: g = Gx[t] + h@Ww; gates; c,h update
//   C) batched output projection out = H@Pw + P_b  (132 GFLOP, bf16 MFMA)
//
// All GEMMs: bf16 MFMA 16x16x32, A row-major [M][K], B pre-transposed [N][K].
// Verified gfx950 layouts: A/B frag: idx=lane&15, k=(lane>>4)*8+j (16B runs);
// C/D: col=lane&15, row=(lane>>4)*4+reg.

typedef __bf16 bf16;
typedef bf16 bf16x8 __attribute__((ext_vector_type(8)));
typedef float f32x4 __attribute__((ext_vector_type(4)));

#define NB 32      // batch
#define NL 64      // seq len
#define NT 63      // timesteps (L-1)
#define NE 512     // emb
#define NS4 2048   // 4*STY
#define NS 512     // STY
#define NH 1024    // HID
#define NG 4096    // 4*HID
#define NV 32000   // vocab
#define MPAD 2048  // padded M (=NB*NT=2016 -> 2048)

__device__ __forceinline__ float sigmoidf_(float x) { return 1.0f / (1.0f + expf(-x)); }

// ---------------- transpose + convert: dst[C][R] = bf16(src[R][C]) -------------
__global__ void k_transpose_cvt(const float* __restrict__ src, bf16* __restrict__ dst,
                                int R, int C) {
  __shared__ float t[32][33];
  int bx = blockIdx.x * 32;  // C tile
  int by = blockIdx.y * 32;  // R tile
  int tx = threadIdx.x & 31, ty = threadIdx.x >> 5;  // ty in 0..7
#pragma unroll
  for (int i = 0; i < 32; i += 8)
    t[ty + i][tx] = src[(size_t)(by + ty + i) * C + (bx + tx)];
  __syncthreads();
#pragma unroll
  for (int i = 0; i < 32; i += 8)
    dst[(size_t)(bx + ty + i) * R + (by + tx)] = (bf16)t[tx][ty + i];
}

// ---------------- embedding gather into time-major X [MPAD][NE] bf16 -----------
// row r = t*32 + b ; rows >= 2016 zeroed.
__global__ void k_gather(const int* __restrict__ rnn, const float* __restrict__ embed,
                         bf16* __restrict__ X) {
  int r = blockIdx.x;
  if (r < NB * NT) {
    int t = r >> 5, b = r & 31;
    int tok = rnn[b * NL + t];
    const float* src = embed + (size_t)tok * NE;
    for (int e = threadIdx.x; e < NE; e += 256) X[(size_t)r * NE + e] = (bf16)src[e];
  } else {
    for (int e = threadIdx.x; e < NE; e += 256) X[(size_t)r * NE + e] = (bf16)0.0f;
  }
}

// ---------------- init c (f32) and h0 (bf16) from sentence_vector --------------
__global__ void k_init(const float* __restrict__ sv, float* __restrict__ c,
                       bf16* __restrict__ h0) {
  int i = blockIdx.x * 256 + threadIdx.x;
  if (i < NB * NH) { c[i] = sv[i]; h0[i] = (bf16)sv[i]; }
}

// ---------------- combined bias V_b + W_b --------------------------------------
__global__ void k_bias2(const float* __restrict__ a, const float* __restrict__ b,
                        float* __restrict__ o) {
  int i = blockIdx.x * 256 + threadIdx.x;
  if (i < NG) o[i] = a[i] + b[i];
}

// ---------------- tiled MFMA GEMM: C = A[M][K] @ Bt[N][K]^T + bias -------------
// 128x128 tile, BK=32, 256 threads (4 waves, 2x2 of 64x64).
// OUT_MODE 0: bf16 C [M][N]; 1: f32 C [M][N]; 2: f32 to d_out with row remap
//   (row<2016: t=row>>5, b=row&31 -> out[(b*63+t)*32000 + col])
template <int OUT_MODE>
__global__ __launch_bounds__(256, 2) void k_gemm(const bf16* __restrict__ A,
                                                 const bf16* __restrict__ Bt,
                                                 const float* __restrict__ bias,
                                                 void* __restrict__ Cp, int K, int N) {
  __shared__ bf16 As[128 * 40];  // rows=m, 32 k-elems + pad to 40
  __shared__ bf16 Bs[128 * 40];  // rows=n
  const int tid = threadIdx.x;
  const int m0 = blockIdx.y * 128, n0 = blockIdx.x * 128;
  const int lane = tid & 63, w = tid >> 6;
  const int l15 = lane & 15, kq = lane >> 4;
  const int m_off = (w & 1) * 64, n_off = (w >> 1) * 64;
  // staging: 512 chunks of 8 bf16 per tile; thread does chunks tid, tid+256
  const int r0 = tid >> 2, kk0 = (tid & 3) * 8;
  const int r1 = (tid + 256) >> 2, kk1 = kk0;  // (q+256)&3 == q&3
  f32x4 acc[4][4] = {};
  for (int k0 = 0; k0 < K; k0 += 32) {
    __syncthreads();
    *(bf16x8*)&As[r0 * 40 + kk0] = *(const bf16x8*)&A[(size_t)(m0 + r0) * K + k0 + kk0];
    *(bf16x8*)&As[r1 * 40 + kk1] = *(const bf16x8*)&A[(size_t)(m0 + r1) * K + k0 + kk1];
    *(bf16x8*)&Bs[r0 * 40 + kk0] = *(const bf16x8*)&Bt[(size_t)(n0 + r0) * K + k0 + kk0];
    *(bf16x8*)&Bs[r1 * 40 + kk1] = *(const bf16x8*)&Bt[(size_t)(n0 + r1) * K + k0 + kk1];
    __syncthreads();
    bf16x8 a[4], b[4];
#pragma unroll
    for (int i = 0; i < 4; i++)
      a[i] = *(const bf16x8*)&As[(m_off + 16 * i + l15) * 40 + kq * 8];
#pragma unroll
    for (int j = 0; j < 4; j++)
      b[j] = *(const bf16x8*)&Bs[(n_off + 16 * j + l15) * 40 + kq * 8];
#pragma unroll
    for (int i = 0; i < 4; i++)
#pragma unroll
      for (int j = 0; j < 4; j++)
        acc[i][j] = __builtin_amdgcn_mfma_f32_16x16x32_bf16(a[i], b[j], acc[i][j], 0, 0, 0);
  }
#pragma unroll
  for (int j = 0; j < 4; j++) {
    const int col = n0 + n_off + 16 * j + l15;
    const float bv = bias[col];
#pragma unroll
    for (int i = 0; i < 4; i++) {
#pragma unroll
      for (int r = 0; r < 4; r++) {
        const int row = m0 + m_off + 16 * i + kq * 4 + r;
        const float v = acc[i][j][r] + bv;
        if (OUT_MODE == 0) {
          ((bf16*)Cp)[(size_t)row * N + col] = (bf16)v;
        } else if (OUT_MODE == 1) {
          ((float*)Cp)[(size_t)row * N + col] = v;
        } else {
          if (row < NB * NT) {
            int t = row >> 5, b = row & 31;
            ((float*)Cp)[((size_t)b * NT + t) * NV + col] = v;
          }
        }
      }
    }
  }
}

// ---------------- fused recurrent step -----------------------------------------
// grid 64 blocks (16 hidden cols each), 256 threads; wave w handles gate w.
// g = Gx_t + h_prev @ Ww ; c' = sig(f)*c + sig(i)*tanh(cg) ; h' = sig(o)*c'
__global__ __launch_bounds__(256) void k_step(const bf16* __restrict__ h_prev,
                                              const bf16* __restrict__ Wt,
                                              const float* __restrict__ Gx,
                                              float* __restrict__ c,
                                              bf16* __restrict__ h_out) {
  __shared__ float gl[4][32][16];
  const int tid = threadIdx.x, lane = tid & 63, g = tid >> 6;
  const int l15 = lane & 15, kq = lane >> 4;
  const int j0 = blockIdx.x * 16;
  f32x4 acc0 = {}, acc1 = {};
  const bf16* wrow = Wt + (size_t)(g * NH + j0 + l15) * NH;
#pragma unroll 8
  for (int k0 = 0; k0 < NH; k0 += 32) {
    bf16x8 a0 = *(const bf16x8*)&h_prev[l15 * NH + k0 + kq * 8];
    bf16x8 a1 = *(const bf16x8*)&h_prev[(16 + l15) * NH + k0 + kq * 8];
    bf16x8 b = *(const bf16x8*)&wrow[k0 + kq * 8];
    acc0 = __builtin_amdgcn_mfma_f32_16x16x32_bf16(a0, b, acc0, 0, 0, 0);
    acc1 = __builtin_amdgcn_mfma_f32_16x16x32_bf16(a1, b, acc1, 0, 0, 0);
  }
#pragma unroll
  for (int r = 0; r < 4; r++) {
    gl[g][kq * 4 + r][l15] = acc0[r];
    gl[g][16 + kq * 4 + r][l15] = acc1[r];
  }
  __syncthreads();
#pragma unroll
  for (int e = tid; e < 512; e += 256) {
    int bb = e >> 4, jj = e & 15, j = j0 + jj;
    float gi = gl[0][bb][jj] + Gx[bb * NG + j];
    float gf = gl[1][bb][jj] + Gx[bb * NG + NH + j];
    float go = gl[2][bb][jj] + Gx[bb * NG + 2 * NH + j];
    float gc = gl[3][bb][jj] + Gx[bb * NG + 3 * NH + j];
    float cp = c[bb * NH + j];
    float cn = sigmoidf_(gf) * cp + sigmoidf_(gi) * tanhf(gc);
    float hn = sigmoidf_(go) * cn;
    c[bb * NH + j] = cn;
    h_out[bb * NH + j] = (bf16)hn;
  }
}

extern "C" void kernel_launch(void* const* d_in, const int* in_sizes, int n_in,
                              void* d_out, int out_size, void* d_ws, size_t ws_size,
                              hipStream_t stream) {
  const int* rnn = (const int*)d_in[0];
  const float* sv = (const float*)d_in[1];
  const float* embed = (const float*)d_in[2];
  const float* U_w = (const float*)d_in[3];
  const float* U_b = (const float*)d_in[4];
  const float* S1_w = (const float*)d_in[5];
  const float* S1_b = (const float*)d_in[6];
  const float* V_w = (const float*)d_in[7];
  const float* V_b = (const float*)d_in[8];
  const float* W_w = (const float*)d_in[9];
  const float* W_b = (const float*)d_in[10];
  const float* P_w = (const float*)d_in[11];
  const float* P_b = (const float*)d_in[12];
  float* out = (float*)d_out;

  char* ws = (char*)d_ws;
  size_t off = 0;
  auto alloc = [&](size_t bytes) -> void* {
    void* p = ws + off;
    off += (bytes + 255) & ~(size_t)255;
    return p;
  };
  bf16* Pt = (bf16*)alloc((size_t)NV * NH * 2);      // 65.5 MB  P_w^T
  float* Gx = (float*)alloc((size_t)MPAD * NG * 4);  // 33.6 MB
  bf16* Ub = (bf16*)alloc((size_t)MPAD * NS4 * 2);   // 8.4 MB   U (bf16)
  bf16* Wt = (bf16*)alloc((size_t)NG * NH * 2);      // 8.4 MB   W_w^T
  bf16* hb = (bf16*)alloc((size_t)(MPAD + 32) * NH * 2);  // 4.3 MB h ring (row0=h0)
  bf16* Vt = (bf16*)alloc((size_t)NG * NS * 2);      // 4.2 MB   V_w^T
  bf16* Xb = (bf16*)alloc((size_t)MPAD * NE * 2);    // 2.1 MB
  bf16* Ut = (bf16*)alloc((size_t)NS4 * NE * 2);     // 2.1 MB   U_w^T
  bf16* S1t = (bf16*)alloc((size_t)NS * NS4 * 2);    // 2.1 MB   S1_w^T
  bf16* Sb = (bf16*)alloc((size_t)MPAD * NS * 2);    // 2.1 MB   S (bf16)
  float* cb = (float*)alloc((size_t)NB * NH * 4);    // c state
  float* vbwb = (float*)alloc((size_t)NG * 4);       // V_b + W_b
  (void)in_sizes; (void)n_in; (void)out_size; (void)ws_size;

  // Phase A0: weight conversion (transpose to [N][K] bf16)
  k_transpose_cvt<<<dim3(NS4 / 32, NE / 32), 256, 0, stream>>>(U_w, Ut, NE, NS4);
  k_transpose_cvt<<<dim3(NS / 32, NS4 / 32), 256, 0, stream>>>(S1_w, S1t, NS4, NS);
  k_transpose_cvt<<<dim3(NG / 32, NS / 32), 256, 0, stream>>>(V_w, Vt, NS, NG);
  k_transpose_cvt<<<dim3(NG / 32, NH / 32), 256, 0, stream>>>(W_w, Wt, NH, NG);
  k_transpose_cvt<<<dim3(NV / 32, NH / 32), 256, 0, stream>>>(P_w, Pt, NH, NV);
  k_bias2<<<NG / 256, 256, 0, stream>>>(V_b, W_b, vbwb);
  k_init<<<(NB * NH + 255) / 256, 256, 0, stream>>>(sv, cb, hb);
  k_gather<<<MPAD, 256, 0, stream>>>(rnn, embed, Xb);

  // Phase A1: batched pre-GEMMs over all (t,b)
  k_gemm<0><<<dim3(NS4 / 128, MPAD / 128), 256, 0, stream>>>(Xb, Ut, U_b, Ub, NE, NS4);
  k_gemm<0><<<dim3(NS / 128, MPAD / 128), 256, 0, stream>>>(Ub, S1t, S1_b, Sb, NS4, NS);
  k_gemm<1><<<dim3(NG / 128, MPAD / 128), 256, 0, stream>>>(Sb, Vt, vbwb, Gx, NS, NG);

  // Phase B: sequential recurrence (h rows: step t reads t*32, writes (t+1)*32)
  for (int t = 0; t < NT; t++) {
    k_step<<<64, 256, 0, stream>>>(hb + (size_t)t * NB * NH, Wt,
                                   Gx + (size_t)t * NB * NG, cb,
                                   hb + (size_t)(t + 1) * NB * NH);
  }

  // Phase C: output projection for all (t,b), remapped to out[b][t][v]
  k_gemm<2><<<dim3(NV / 128, MPAD / 128), 256, 0, stream>>>(hb + (size_t)NB * NH, Pt,
                                                            P_b, out, NH, NV);
}

// Round 2
// 1140.801 us; speedup vs baseline: 1.4100x; 1.4100x over previous
//
#include <hip/hip_runtime.h>
#include <hip/hip_bf16.h>

// FactoredLSTM on MI355X (gfx950).
// Phases:
//   A) convert/transpose weights fp32->bf16 [N][K]; gather embeddings; batched
//      GEMM chain U = X@Uw, S = U@S1w, Gx = S@Vw + (V_b + W_b)  (no h dependence)
//   B) ONE persistent kernel: 63 steps, grid-synced; W slice held in VGPRs,
//      c-state in LDS, h ring in global bf16.
//   C) batched output projection out = H@Pw + P_b  (134 GFLOP, bf16 MFMA,
//      m97-style global_load_lds staging)
//
// MFMA 16x16x32 bf16. A row-major [M][K], B pre-transposed [N][K].
// Layouts (verified): A/B frag idx=lane&15, k=(lane>>4)*8+j; C/D col=lane&15,
// row=(lane>>4)*4+reg.

typedef __bf16 bf16;
typedef bf16 bf16x8 __attribute__((ext_vector_type(8)));
typedef float f32x4 __attribute__((ext_vector_type(4)));

#define NB 32      // batch
#define NL 64      // seq len
#define NT 63      // timesteps (L-1)
#define NE 512     // emb
#define NS4 2048   // 4*STY
#define NS 512     // STY
#define NH 1024    // HID
#define NG 4096    // 4*HID
#define NV 32000   // vocab
#define MPAD 2048  // padded M (=NB*NT=2016 -> 2048)

__device__ __forceinline__ float sigmoidf_(float x) { return 1.0f / (1.0f + expf(-x)); }

// async global->LDS, 16B per lane; lds base must be wave-uniform (HW: base + lane*16)
__device__ __forceinline__ void gload_lds16(const bf16* g, bf16* l) {
  __builtin_amdgcn_global_load_lds(
      (const __attribute__((address_space(1))) unsigned int*)g,
      (__attribute__((address_space(3))) unsigned int*)l, 16, 0, 0);
}

// ---------------- transpose + convert: dst[C][R] = bf16(src[R][C]) -------------
__global__ void k_transpose_cvt(const float* __restrict__ src, bf16* __restrict__ dst,
                                int R, int C) {
  __shared__ float t[32][33];
  int bx = blockIdx.x * 32;  // C tile
  int by = blockIdx.y * 32;  // R tile
  int tx = threadIdx.x & 31, ty = threadIdx.x >> 5;  // ty in 0..7
#pragma unroll
  for (int i = 0; i < 32; i += 8)
    t[ty + i][tx] = src[(size_t)(by + ty + i) * C + (bx + tx)];
  __syncthreads();
#pragma unroll
  for (int i = 0; i < 32; i += 8)
    dst[(size_t)(bx + ty + i) * R + (by + tx)] = (bf16)t[tx][ty + i];
}

// ---------------- embedding gather into time-major X [MPAD][NE] bf16 -----------
__global__ void k_gather(const int* __restrict__ rnn, const float* __restrict__ embed,
                         bf16* __restrict__ X) {
  int r = blockIdx.x;
  if (r < NB * NT) {
    int t = r >> 5, b = r & 31;
    int tok = rnn[b * NL + t];
    const float* src = embed + (size_t)tok * NE;
    for (int e = threadIdx.x; e < NE; e += 256) X[(size_t)r * NE + e] = (bf16)src[e];
  } else {
    for (int e = threadIdx.x; e < NE; e += 256) X[(size_t)r * NE + e] = (bf16)0.0f;
  }
}

// ---------------- init h0 (bf16) from sentence_vector; zero grid barrier -------
__global__ void k_init(const float* __restrict__ sv, bf16* __restrict__ h0,
                       unsigned* __restrict__ bar) {
  int i = blockIdx.x * 256 + threadIdx.x;
  if (i == 0) *bar = 0u;
  if (i < NB * NH) h0[i] = (bf16)sv[i];
}

// ---------------- combined bias V_b + W_b --------------------------------------
__global__ void k_bias2(const float* __restrict__ a, const float* __restrict__ b,
                        float* __restrict__ o) {
  int i = blockIdx.x * 256 + threadIdx.x;
  if (i < NG) o[i] = a[i] + b[i];
}

// ---------------- tiled MFMA GEMM: C = A[M][K] @ Bt[N][K]^T + bias -------------
// 128x128 tile, BK=32, 256 threads (4 waves, 2x2 of 64x64), m97-style
// global_load_lds(16) staging into unpadded stride-32 LDS.
// OUT_MODE 0: bf16 C [M][N]; 1: f32 C [M][N]; 2: f32 to d_out with row remap
template <int OUT_MODE>
__global__ __launch_bounds__(256, 2) void k_gemm(const bf16* __restrict__ A,
                                                 const bf16* __restrict__ Bt,
                                                 const float* __restrict__ bias,
                                                 void* __restrict__ Cp, int K, int N) {
  __shared__ bf16 As[128 * 32];
  __shared__ bf16 Bs[128 * 32];
  const int tid = threadIdx.x;
  const int m0 = blockIdx.y * 128, n0 = blockIdx.x * 128;
  const int lane = tid & 63, w = tid >> 6;
  const int l15 = lane & 15, kq = lane >> 4;
  const int m_off = (w & 1) * 64, n_off = (w >> 1) * 64;
  // staging: 8 chunks of 1KB per tile (wave-chunk = 64 lanes x 16B); wave w
  // does chunks 2w, 2w+1 of A and of B. chunk c, lane l -> row c*16+(l>>2),
  // k-offset (l&3)*8; LDS dest base As + c*512 elems (contiguous row-major).
  const int c0 = 2 * w, c1 = 2 * w + 1;
  const int sub = lane >> 2, kkl = (lane & 3) * 8;
  const bf16* pA0 = A + (size_t)(m0 + c0 * 16 + sub) * K + kkl;
  const bf16* pA1 = A + (size_t)(m0 + c1 * 16 + sub) * K + kkl;
  const bf16* pB0 = Bt + (size_t)(n0 + c0 * 16 + sub) * K + kkl;
  const bf16* pB1 = Bt + (size_t)(n0 + c1 * 16 + sub) * K + kkl;
  f32x4 acc[4][4] = {};
  for (int k0 = 0; k0 < K; k0 += 32) {
    __syncthreads();
    gload_lds16(pA0 + k0, &As[c0 * 512]);
    gload_lds16(pA1 + k0, &As[c1 * 512]);
    gload_lds16(pB0 + k0, &Bs[c0 * 512]);
    gload_lds16(pB1 + k0, &Bs[c1 * 512]);
    __syncthreads();
    bf16x8 a[4], b[4];
#pragma unroll
    for (int i = 0; i < 4; i++)
      a[i] = *(const bf16x8*)&As[(m_off + 16 * i + l15) * 32 + kq * 8];
#pragma unroll
    for (int j = 0; j < 4; j++)
      b[j] = *(const bf16x8*)&Bs[(n_off + 16 * j + l15) * 32 + kq * 8];
#pragma unroll
    for (int i = 0; i < 4; i++)
#pragma unroll
      for (int j = 0; j < 4; j++)
        acc[i][j] = __builtin_amdgcn_mfma_f32_16x16x32_bf16(a[i], b[j], acc[i][j], 0, 0, 0);
  }
#pragma unroll
  for (int j = 0; j < 4; j++) {
    const int col = n0 + n_off + 16 * j + l15;
    const float bv = bias[col];
#pragma unroll
    for (int i = 0; i < 4; i++) {
#pragma unroll
      for (int r = 0; r < 4; r++) {
        const int row = m0 + m_off + 16 * i + kq * 4 + r;
        const float v = acc[i][j][r] + bv;
        if (OUT_MODE == 0) {
          ((bf16*)Cp)[(size_t)row * N + col] = (bf16)v;
        } else if (OUT_MODE == 1) {
          ((float*)Cp)[(size_t)row * N + col] = v;
        } else {
          if (row < NB * NT) {
            int t = row >> 5, b = row & 31;
            ((float*)Cp)[((size_t)b * NT + t) * NV + col] = v;
          }
        }
      }
    }
  }
}

// ---------------- persistent recurrence ----------------------------------------
// grid 128 blocks = 64 colgroups x 2 batch-halves; 256 threads = 4 waves
// (wave = gate). W slice (16 cols x 1024) held in 128 VGPRs per lane across all
// 63 steps. c-state in LDS. h ring in global bf16. Grid barrier between steps
// (device-scope atomics, monotonic target; all 128 blocks trivially co-resident
// on 256 CUs).
__global__ __launch_bounds__(256, 1) void k_rnn(const bf16* __restrict__ Wt,
                                                const float* __restrict__ Gx,
                                                const float* __restrict__ sv,
                                                bf16* __restrict__ hb,
                                                unsigned* __restrict__ bar) {
  __shared__ bf16 hs[16 * 1032];   // h batch-half, row stride 1032 (bank rotate)
  __shared__ float gl[4][16][16];  // gate partials
  __shared__ float cs[16][16];     // c state
  const int tid = threadIdx.x;
  const int lane = tid & 63, g = tid >> 6;
  const int l15 = lane & 15, kq = lane >> 4;
  const int cg = blockIdx.x >> 1;   // colgroup 0..63
  const int bh = blockIdx.x & 1;    // batch half
  const int j0 = cg * 16;
  const int brow0 = bh * 16;
  const int bb_e = tid >> 4, jj_e = tid & 15;  // epilogue assignment
  // c init
  cs[bb_e][jj_e] = sv[(brow0 + bb_e) * NH + j0 + jj_e];
  // W slice -> registers: lane holds wrow[k*32 + kq*8 .. +7] for k=0..31
  const bf16* wrow = Wt + (size_t)(g * NH + j0 + l15) * NH;
  bf16x8 breg[32];
#pragma unroll
  for (int k = 0; k < 32; k++) breg[k] = *(const bf16x8*)&wrow[k * 32 + kq * 8];
  unsigned target = 0;
  for (int t = 0; t < NT; t++) {
    // stage h batch-half (16 rows x 1024) into LDS, coalesced 16B chunks
    const bf16* hp = hb + (size_t)t * NB * NH + (size_t)brow0 * NH;
    __syncthreads();  // vs previous iteration's hs reads (no-op at t=0)
#pragma unroll
    for (int q = 0; q < 8; q++) {
      int idx = tid + 256 * q;        // 2048 chunks of 8 elems
      int row = idx >> 7, col = (idx & 127) * 8;
      *(bf16x8*)&hs[row * 1032 + col] = *(const bf16x8*)&hp[row * NH + col];
    }
    __syncthreads();
    f32x4 acc = {};
#pragma unroll
    for (int k = 0; k < 32; k++) {
      bf16x8 a = *(const bf16x8*)&hs[l15 * 1032 + k * 32 + kq * 8];
      acc = __builtin_amdgcn_mfma_f32_16x16x32_bf16(a, breg[k], acc, 0, 0, 0);
    }
#pragma unroll
    for (int r = 0; r < 4; r++) gl[g][kq * 4 + r][l15] = acc[r];
    __syncthreads();
    // epilogue: thread -> (batch bb_e, col jj_e)
    {
      const int j = j0 + jj_e;
      const float* gx = Gx + (size_t)t * NB * NG + (size_t)(brow0 + bb_e) * NG;
      float gi = gl[0][bb_e][jj_e] + gx[j];
      float gf = gl[1][bb_e][jj_e] + gx[NH + j];
      float go = gl[2][bb_e][jj_e] + gx[2 * NH + j];
      float gc = gl[3][bb_e][jj_e] + gx[3 * NH + j];
      float cp = cs[bb_e][jj_e];
      float cn = sigmoidf_(gf) * cp + sigmoidf_(gi) * tanhf(gc);
      float hn = sigmoidf_(go) * cn;
      cs[bb_e][jj_e] = cn;
      hb[(size_t)(t + 1) * NB * NH + (size_t)(brow0 + bb_e) * NH + j] = (bf16)hn;
    }
    // grid barrier (skip after last step; stream order covers Phase C)
    if (t + 1 < NT) {
      target += gridDim.x;
      __syncthreads();
      if (tid == 0) {
        __hip_atomic_fetch_add(bar, 1u, __ATOMIC_ACQ_REL, __HIP_MEMORY_SCOPE_AGENT);
        while (__hip_atomic_load(bar, __ATOMIC_ACQUIRE, __HIP_MEMORY_SCOPE_AGENT) <
               target)
          __builtin_amdgcn_s_sleep(2);
      }
      __syncthreads();
    }
  }
}

extern "C" void kernel_launch(void* const* d_in, const int* in_sizes, int n_in,
                              void* d_out, int out_size, void* d_ws, size_t ws_size,
                              hipStream_t stream) {
  const int* rnn = (const int*)d_in[0];
  const float* sv = (const float*)d_in[1];
  const float* embed = (const float*)d_in[2];
  const float* U_w = (const float*)d_in[3];
  const float* U_b = (const float*)d_in[4];
  const float* S1_w = (const float*)d_in[5];
  const float* S1_b = (const float*)d_in[6];
  const float* V_w = (const float*)d_in[7];
  const float* V_b = (const float*)d_in[8];
  const float* W_w = (const float*)d_in[9];
  const float* W_b = (const float*)d_in[10];
  const float* P_w = (const float*)d_in[11];
  const float* P_b = (const float*)d_in[12];
  float* out = (float*)d_out;

  char* ws = (char*)d_ws;
  size_t off = 0;
  auto alloc = [&](size_t bytes) -> void* {
    void* p = ws + off;
    off += (bytes + 255) & ~(size_t)255;
    return p;
  };
  bf16* Pt = (bf16*)alloc((size_t)NV * NH * 2);           // P_w^T
  float* Gx = (float*)alloc((size_t)MPAD * NG * 4);       // gate preactivations
  bf16* Ub = (bf16*)alloc((size_t)MPAD * NS4 * 2);        // U (bf16)
  bf16* Wt = (bf16*)alloc((size_t)NG * NH * 2);           // W_w^T
  bf16* hb = (bf16*)alloc((size_t)(MPAD + 32) * NH * 2);  // h ring (row0=h0)
  bf16* Vt = (bf16*)alloc((size_t)NG * NS * 2);           // V_w^T
  bf16* Xb = (bf16*)alloc((size_t)MPAD * NE * 2);         // gathered emb
  bf16* Ut = (bf16*)alloc((size_t)NS4 * NE * 2);          // U_w^T
  bf16* S1t = (bf16*)alloc((size_t)NS * NS4 * 2);         // S1_w^T
  bf16* Sb = (bf16*)alloc((size_t)MPAD * NS * 2);         // S (bf16)
  float* vbwb = (float*)alloc((size_t)NG * 4);            // V_b + W_b
  unsigned* bar = (unsigned*)alloc(256);                  // grid barrier
  (void)in_sizes; (void)n_in; (void)out_size; (void)ws_size;

  // Phase A0: weight conversion (transpose to [N][K] bf16)
  k_transpose_cvt<<<dim3(NS4 / 32, NE / 32), 256, 0, stream>>>(U_w, Ut, NE, NS4);
  k_transpose_cvt<<<dim3(NS / 32, NS4 / 32), 256, 0, stream>>>(S1_w, S1t, NS4, NS);
  k_transpose_cvt<<<dim3(NG / 32, NS / 32), 256, 0, stream>>>(V_w, Vt, NS, NG);
  k_transpose_cvt<<<dim3(NG / 32, NH / 32), 256, 0, stream>>>(W_w, Wt, NH, NG);
  k_transpose_cvt<<<dim3(NV / 32, NH / 32), 256, 0, stream>>>(P_w, Pt, NH, NV);
  k_bias2<<<NG / 256, 256, 0, stream>>>(V_b, W_b, vbwb);
  k_init<<<(NB * NH + 255) / 256, 256, 0, stream>>>(sv, hb, bar);
  k_gather<<<MPAD, 256, 0, stream>>>(rnn, embed, Xb);

  // Phase A1: batched pre-GEMMs over all (t,b)
  k_gemm<0><<<dim3(NS4 / 128, MPAD / 128), 256, 0, stream>>>(Xb, Ut, U_b, Ub, NE, NS4);
  k_gemm<0><<<dim3(NS / 128, MPAD / 128), 256, 0, stream>>>(Ub, S1t, S1_b, Sb, NS4, NS);
  k_gemm<1><<<dim3(NG / 128, MPAD / 128), 256, 0, stream>>>(Sb, Vt, vbwb, Gx, NS, NG);

  // Phase B: persistent recurrence (single dispatch, internal grid sync)
  k_rnn<<<128, 256, 0, stream>>>(Wt, Gx, sv, hb, bar);

  // Phase C: output projection for all (t,b), remapped to out[b][t][v]
  k_gemm<2><<<dim3(NV / 128, MPAD / 128), 256, 0, stream>>>(hb + (size_t)NB * NH, Pt,
                                                            P_b, out, NH, NV);
}